// Round 4
// baseline (246.550 us; speedup 1.0000x reference)
//
#include <hip/hip_runtime.h>

#define PI_F 3.14159f

// ---------------------------------------------------------------------------
// Kernel A: per-batch MLP head -> per-channel PRE-SCALED affine params.
// 4 batches per block, 256 threads. Phase 1 keeps para in registers and
// broadcasts with v_readlane (no LDS). params layout: [B][20][8] =
// (P0..P5, 0, 0):  ix = P0*X + P1*Y + P2 ; iy = P3*X + P4*Y + P5
// with grid_sample *9+8.5 scaling and the +1 LDS-pad shift folded in.
// ---------------------------------------------------------------------------
__global__ __launch_bounds__(256) void params_kernel(
    const float* __restrict__ pc, const float* __restrict__ W1, const float* __restrict__ b1,
    const float* __restrict__ Ws, const float* __restrict__ bs,
    const float* __restrict__ Wr, const float* __restrict__ br,
    const float* __restrict__ Wt, const float* __restrict__ bt,
    float* __restrict__ params)
{
    __shared__ float hbuf[4][260];
    __shared__ float raw[4][80];

    const int t    = threadIdx.x;
    const int lane = t & 63;
    const int b0   = blockIdx.x * 4;

    float pval[4][4];
    #pragma unroll
    for (int g = 0; g < 4; ++g)
        #pragma unroll
        for (int c = 0; c < 4; ++c)
            pval[g][c] = pc[(size_t)(b0 + g) * 256 + c * 64 + lane];

    float acc[4];
    #pragma unroll
    for (int g = 0; g < 4; ++g) acc[g] = b1[t];

    #pragma unroll
    for (int c = 0; c < 4; ++c) {
        for (int kk = 0; kk < 64; ++kk) {
            float w = W1[(c * 64 + kk) * 256 + t];
            #pragma unroll
            for (int g = 0; g < 4; ++g) {
                float pk = __int_as_float(
                    __builtin_amdgcn_readlane(__float_as_int(pval[g][c]), kk));
                acc[g] = fmaf(pk, w, acc[g]);
            }
        }
    }
    #pragma unroll
    for (int g = 0; g < 4; ++g) hbuf[g][t] = fmaxf(acc[g], 0.0f);
    __syncthreads();

    for (int task = t; task < 320; task += 256) {
        int g   = task / 80;
        int col = task - g * 80;
        const float* Wcol;
        float bias;
        int stride;
        if (col < 20)      { Wcol = Ws + col;        bias = bs[col];      stride = 20; }
        else if (col < 40) { Wcol = Wr + (col - 20); bias = br[col - 20]; stride = 20; }
        else               { Wcol = Wt + (col - 40); bias = bt[col - 40]; stride = 40; }
        const float4* h4 = (const float4*)hbuf[g];
        float a = bias;
        for (int k4 = 0; k4 < 64; ++k4) {
            float4 h = h4[k4];
            int k = k4 * 4;
            a = fmaf(h.x, Wcol[k * stride], a);
            a = fmaf(h.y, Wcol[(k + 1) * stride], a);
            a = fmaf(h.z, Wcol[(k + 2) * stride], a);
            a = fmaf(h.w, Wcol[(k + 3) * stride], a);
        }
        raw[g][col] = a;
    }
    __syncthreads();

    for (int task = t; task < 80; task += 256) {
        int g = task / 20;
        int f = task - g * 20;
        float sc  = 2.0f / (1.0f + expf(-raw[g][f]));
        float ang = PI_F * tanhf(raw[g][20 + f]);
        float tx  = tanhf(raw[g][40 + 2 * f]);
        float ty  = tanhf(raw[g][40 + 2 * f + 1]);
        float c = cosf(ang), s = sinf(ang);
        float* o = params + ((size_t)(b0 + g) * 20 + f) * 8;
        o[0] = 9.0f * sc * c;  o[1] = -9.0f * sc * s;  o[2] = fmaf(9.0f, tx, 9.5f);
        o[3] = 9.0f * sc * s;  o[4] =  9.0f * sc * c;  o[5] = fmaf(9.0f, ty, 9.5f);
        o[6] = 0.0f;           o[7] = 0.0f;
    }
}

// ---------------------------------------------------------------------------
// Kernel B: one block (384 threads) per batch.
// Staging pre-blends the fixed z-interpolation into 20 channel images stored
// as [20][y:20][x:20] with a 1-cell zero pad (32 KB -> 5 blocks/CU).
// Zero-padding via coordinate clamp: padded ix,iy clamped to [0,19]; at the
// clamp boundary the corresponding tap weight is exactly 0, so out-of-range
// contributions vanish. Taps s[0],s[1],s[20],s[21] -> 2x ds_read2_b32.
// Channels processed in groups of 4 with all 8 LDS reads issued before use.
// ---------------------------------------------------------------------------
template<int D>
struct Stage {
    static constexpr int   Z0  = (D == 0) ? -1 : (40 * D - 19) / 38;
    static constexpr float W1v = (float)((40.0 * D - 19.0) / 38.0 - (double)Z0);
    static constexpr float W0v = 1.0f - W1v;
    static constexpr bool  V0  = (Z0 >= 0);
    static constexpr bool  V1  = (Z0 + 1 <= 19);

    static __device__ __forceinline__ void go(const float (&v)[20], float* vol, int w) {
        float I;
        if constexpr (V0 && V1)  I = fmaf(v[Z0], W0v, v[Z0 + 1] * W1v);
        else if constexpr (V0)   I = v[Z0] * W0v;
        else                     I = v[(Z0 + 1) < 0 ? 0 : (Z0 + 1)] * W1v;
        vol[D * 400 + w] = I;
        Stage<D + 1>::go(v, vol, w);
    }
};
template<> struct Stage<20> {
    static __device__ __forceinline__ void go(const float (&)[20], float*, int) {}
};

__global__ __launch_bounds__(384, 8) void sample_kernel(
    const float* __restrict__ fmap, const float* __restrict__ params,
    float* __restrict__ out)
{
    __shared__ __align__(16) float vol[8024];   // [20][20][20] + guard (32 KB)

    const int b = blockIdx.x;
    const int t = threadIdx.x;

    float4* v4 = (float4*)vol;
    for (int i = t; i < 2006; i += 384) v4[i] = make_float4(0.f, 0.f, 0.f, 0.f);
    __syncthreads();

    int yy = 0, xx = 0;
    if (t < 324) {
        yy = t / 18;
        xx = t - yy * 18;
        const float* fb = fmap + (size_t)b * 6480;
        float v[20];
        #pragma unroll
        for (int dz = 0; dz < 20; ++dz) v[dz] = fb[dz * 324 + t];
        const int w = (yy + 1) * 20 + (xx + 1);
        Stage<0>::go(v, vol, w);
    }
    __syncthreads();

    if (t >= 324) return;

    const float X = xx * (2.0f / 17.0f) - 1.0f;
    const float Y = yy * (2.0f / 17.0f) - 1.0f;
    const float* pb = params + (size_t)b * 160;
    float* ob = out + (size_t)b * 6480 + t;

    #pragma unroll
    for (int G = 0; G < 5; ++G) {               // 5 groups x 4 channels
        float u1[4], v1[4];
        int base[4];
        #pragma unroll
        for (int j = 0; j < 4; ++j) {
            const int D = G * 4 + j;
            float4 pA = *(const float4*)(pb + D * 8);
            float2 pB = *(const float2*)(pb + D * 8 + 4);
            float ix = fmaf(pA.x, X, fmaf(pA.y, Y, pA.z));   // padded coords
            float iy = fmaf(pA.w, X, fmaf(pB.x, Y, pB.y));
            ix = fminf(fmaxf(ix, 0.0f), 19.0f);
            iy = fminf(fmaxf(iy, 0.0f), 19.0f);
            float fx = floorf(ix), fy = floorf(iy);
            u1[j] = ix - fx;
            v1[j] = iy - fy;
            base[j] = D * 400 + (int)fy * 20 + (int)fx;
        }
        float t00[4], t01[4], t10[4], t11[4];
        #pragma unroll
        for (int j = 0; j < 4; ++j) {
            const float* s = vol + base[j];
            t00[j] = s[0]; t01[j] = s[1]; t10[j] = s[20]; t11[j] = s[21];
        }
        #pragma unroll
        for (int j = 0; j < 4; ++j) {
            float u0 = 1.0f - u1[j], v0 = 1.0f - v1[j];
            float r = fmaf(fmaf(t01[j], u1[j], t00[j] * u0), v0,
                           fmaf(t11[j], u1[j], t10[j] * u0) * v1[j]);
            ob[(G * 4 + j) * 324] = r;
        }
    }
}

extern "C" void kernel_launch(void* const* d_in, const int* in_sizes, int n_in,
                              void* d_out, int out_size, void* d_ws, size_t ws_size,
                              hipStream_t stream)
{
    const float* fmap = (const float*)d_in[0];
    const float* pc   = (const float*)d_in[1];
    const float* W1   = (const float*)d_in[2];
    const float* b1   = (const float*)d_in[3];
    const float* Ws   = (const float*)d_in[4];
    const float* bs   = (const float*)d_in[5];
    const float* Wr   = (const float*)d_in[6];
    const float* br   = (const float*)d_in[7];
    const float* Wt   = (const float*)d_in[8];
    const float* bt   = (const float*)d_in[9];
    float* out    = (float*)d_out;
    float* params = (float*)d_ws;     // B*20*8 floats

    const int B = in_sizes[0] / (20 * 18 * 18);   // 4096

    params_kernel<<<B / 4, 256, 0, stream>>>(pc, W1, b1, Ws, bs, Wr, br, Wt, bt, params);
    sample_kernel<<<B, 384, 0, stream>>>(fmap, params, out);
}

// Round 5
// 242.628 us; speedup vs baseline: 1.0162x; 1.0162x over previous
//
#include <hip/hip_runtime.h>

#define PI_F 3.14159f

// ---------------------------------------------------------------------------
// Kernel A: per-batch MLP head -> per-channel PRE-SCALED affine params.
// 4 batches per block, 256 threads. Phase 1 keeps para in registers and
// broadcasts with v_readlane (no LDS). params layout: [B][20][8] =
// (P0..P5, 0, 0):  ix = P0*X + P1*Y + P2 ; iy = P3*X + P4*Y + P5
// with grid_sample *9+8.5 scaling and the +1 LDS-pad shift folded in.
// ---------------------------------------------------------------------------
__global__ __launch_bounds__(256) void params_kernel(
    const float* __restrict__ pc, const float* __restrict__ W1, const float* __restrict__ b1,
    const float* __restrict__ Ws, const float* __restrict__ bs,
    const float* __restrict__ Wr, const float* __restrict__ br,
    const float* __restrict__ Wt, const float* __restrict__ bt,
    float* __restrict__ params)
{
    __shared__ float hbuf[4][260];
    __shared__ float raw[4][80];

    const int t    = threadIdx.x;
    const int lane = t & 63;
    const int b0   = blockIdx.x * 4;

    float pval[4][4];
    #pragma unroll
    for (int g = 0; g < 4; ++g)
        #pragma unroll
        for (int c = 0; c < 4; ++c)
            pval[g][c] = pc[(size_t)(b0 + g) * 256 + c * 64 + lane];

    float acc[4];
    #pragma unroll
    for (int g = 0; g < 4; ++g) acc[g] = b1[t];

    #pragma unroll
    for (int c = 0; c < 4; ++c) {
        for (int kk = 0; kk < 64; ++kk) {
            float w = W1[(c * 64 + kk) * 256 + t];
            #pragma unroll
            for (int g = 0; g < 4; ++g) {
                float pk = __int_as_float(
                    __builtin_amdgcn_readlane(__float_as_int(pval[g][c]), kk));
                acc[g] = fmaf(pk, w, acc[g]);
            }
        }
    }
    #pragma unroll
    for (int g = 0; g < 4; ++g) hbuf[g][t] = fmaxf(acc[g], 0.0f);
    __syncthreads();

    for (int task = t; task < 320; task += 256) {
        int g   = task / 80;
        int col = task - g * 80;
        const float* Wcol;
        float bias;
        int stride;
        if (col < 20)      { Wcol = Ws + col;        bias = bs[col];      stride = 20; }
        else if (col < 40) { Wcol = Wr + (col - 20); bias = br[col - 20]; stride = 20; }
        else               { Wcol = Wt + (col - 40); bias = bt[col - 40]; stride = 40; }
        const float4* h4 = (const float4*)hbuf[g];
        float a = bias;
        for (int k4 = 0; k4 < 64; ++k4) {
            float4 h = h4[k4];
            int k = k4 * 4;
            a = fmaf(h.x, Wcol[k * stride], a);
            a = fmaf(h.y, Wcol[(k + 1) * stride], a);
            a = fmaf(h.z, Wcol[(k + 2) * stride], a);
            a = fmaf(h.w, Wcol[(k + 3) * stride], a);
        }
        raw[g][col] = a;
    }
    __syncthreads();

    for (int task = t; task < 80; task += 256) {
        int g = task / 20;
        int f = task - g * 20;
        float sc  = 2.0f / (1.0f + expf(-raw[g][f]));
        float ang = PI_F * tanhf(raw[g][20 + f]);
        float tx  = tanhf(raw[g][40 + 2 * f]);
        float ty  = tanhf(raw[g][40 + 2 * f + 1]);
        float c = cosf(ang), s = sinf(ang);
        float* o = params + ((size_t)(b0 + g) * 20 + f) * 8;
        o[0] = 9.0f * sc * c;  o[1] = -9.0f * sc * s;  o[2] = fmaf(9.0f, tx, 9.5f);
        o[3] = 9.0f * sc * s;  o[4] =  9.0f * sc * c;  o[5] = fmaf(9.0f, ty, 9.5f);
        o[6] = 0.0f;           o[7] = 0.0f;
    }
}

// ---------------------------------------------------------------------------
// Kernel B: one block (384 threads) per batch.
// Staging pre-blends the fixed z-interpolation into 20 channel images stored
// as [20][y:20][x:20] with a 1-cell zero pad. Per-channel affine params are
// ALSO staged into LDS (160 floats) so the per-group critical path is pure
// LDS (uniform broadcast ds_read) instead of a VMEM round-trip per group.
// Total LDS = (8024 + 168)*4 = 32,768 B -> 5 blocks/CU.
// Zero-padding via coordinate clamp: padded ix,iy clamped to [0,19]; at the
// clamp boundary the corresponding tap weight is exactly 0. Taps
// s[0],s[1],s[20],s[21] -> 2x ds_read2_b32 per channel.
// ---------------------------------------------------------------------------
template<int D>
struct Stage {
    static constexpr int   Z0  = (D == 0) ? -1 : (40 * D - 19) / 38;
    static constexpr float W1v = (float)((40.0 * D - 19.0) / 38.0 - (double)Z0);
    static constexpr float W0v = 1.0f - W1v;
    static constexpr bool  V0  = (Z0 >= 0);
    static constexpr bool  V1  = (Z0 + 1 <= 19);

    static __device__ __forceinline__ void go(const float (&v)[20], float* vol, int w) {
        float I;
        if constexpr (V0 && V1)  I = fmaf(v[Z0], W0v, v[Z0 + 1] * W1v);
        else if constexpr (V0)   I = v[Z0] * W0v;
        else                     I = v[(Z0 + 1) < 0 ? 0 : (Z0 + 1)] * W1v;
        vol[D * 400 + w] = I;
        Stage<D + 1>::go(v, vol, w);
    }
};
template<> struct Stage<20> {
    static __device__ __forceinline__ void go(const float (&)[20], float*, int) {}
};

__global__ __launch_bounds__(384, 8) void sample_kernel(
    const float* __restrict__ fmap, const float* __restrict__ params,
    float* __restrict__ out)
{
    // one allocation: vol [8024] then prm [160] then 8 pad = 8192 floats = 32 KB
    __shared__ __align__(16) float lds[8192];
    float* vol = lds;
    float* prm = lds + 8024;

    const int b = blockIdx.x;
    const int t = threadIdx.x;

    float4* v4 = (float4*)vol;
    for (int i = t; i < 2006; i += 384) v4[i] = make_float4(0.f, 0.f, 0.f, 0.f);
    if (t < 40)
        ((float4*)prm)[t] = ((const float4*)(params + (size_t)b * 160))[t];
    __syncthreads();

    int yy = 0, xx = 0;
    if (t < 324) {
        yy = t / 18;
        xx = t - yy * 18;
        const float* fb = fmap + (size_t)b * 6480;
        float v[20];
        #pragma unroll
        for (int dz = 0; dz < 20; ++dz) v[dz] = fb[dz * 324 + t];
        const int w = (yy + 1) * 20 + (xx + 1);
        Stage<0>::go(v, vol, w);
    }
    __syncthreads();

    if (t >= 324) return;

    const float X = xx * (2.0f / 17.0f) - 1.0f;
    const float Y = yy * (2.0f / 17.0f) - 1.0f;
    float* ob = out + (size_t)b * 6480 + t;

    #pragma unroll
    for (int G = 0; G < 5; ++G) {               // 5 groups x 4 channels
        float u1[4], v1[4];
        int base[4];
        #pragma unroll
        for (int j = 0; j < 4; ++j) {
            const int D = G * 4 + j;
            float4 pA = *(const float4*)(prm + D * 8);      // ds_read_b128, broadcast
            float2 pB = *(const float2*)(prm + D * 8 + 4);  // ds_read_b64, broadcast
            float ix = fmaf(pA.x, X, fmaf(pA.y, Y, pA.z));  // padded coords
            float iy = fmaf(pA.w, X, fmaf(pB.x, Y, pB.y));
            ix = fminf(fmaxf(ix, 0.0f), 19.0f);
            iy = fminf(fmaxf(iy, 0.0f), 19.0f);
            float fx = floorf(ix), fy = floorf(iy);
            u1[j] = ix - fx;
            v1[j] = iy - fy;
            base[j] = D * 400 + (int)fy * 20 + (int)fx;
        }
        float t00[4], t01[4], t10[4], t11[4];
        #pragma unroll
        for (int j = 0; j < 4; ++j) {
            const float* s = vol + base[j];
            t00[j] = s[0]; t01[j] = s[1]; t10[j] = s[20]; t11[j] = s[21];
        }
        #pragma unroll
        for (int j = 0; j < 4; ++j) {
            float u0 = 1.0f - u1[j], v0 = 1.0f - v1[j];
            float r = fmaf(fmaf(t01[j], u1[j], t00[j] * u0), v0,
                           fmaf(t11[j], u1[j], t10[j] * u0) * v1[j]);
            ob[(G * 4 + j) * 324] = r;
        }
    }
}

extern "C" void kernel_launch(void* const* d_in, const int* in_sizes, int n_in,
                              void* d_out, int out_size, void* d_ws, size_t ws_size,
                              hipStream_t stream)
{
    const float* fmap = (const float*)d_in[0];
    const float* pc   = (const float*)d_in[1];
    const float* W1   = (const float*)d_in[2];
    const float* b1   = (const float*)d_in[3];
    const float* Ws   = (const float*)d_in[4];
    const float* bs   = (const float*)d_in[5];
    const float* Wr   = (const float*)d_in[6];
    const float* br   = (const float*)d_in[7];
    const float* Wt   = (const float*)d_in[8];
    const float* bt   = (const float*)d_in[9];
    float* out    = (float*)d_out;
    float* params = (float*)d_ws;     // B*20*8 floats

    const int B = in_sizes[0] / (20 * 18 * 18);   // 4096

    params_kernel<<<B / 4, 256, 0, stream>>>(pc, W1, b1, Ws, bs, Wr, br, Wt, bt, params);
    sample_kernel<<<B, 384, 0, stream>>>(fmap, params, out);
}